// Round 4
// baseline (268.282 us; speedup 1.0000x reference)
//
#include <hip/hip_runtime.h>
#include <hip/hip_bf16.h>

// NCC loss: five 9x9x9 box sums over (2,1,160,160,160) fp32, fully fused.
// Block owns 16x16 (h,w) tile, streams 20 outputs along D; D-window ring in
// registers (slot index compile-time via outer x unrolled-9 loop).
// Phase A: float4 halo staging (chunk-aligned OOB predication).
// Phase B: sliding 9-tap row sums, 96 threads x 4 outputs, EXPLICIT SCALARS
//          ONLY (round-3's indexable locals spilled to scratch: 125 MB of
//          WRITE_SIZE -> this version has zero indexable locals).
// Phase C: 9-tap column sums, 1 output/thread.
// Single-buffered LDS is race-free with the A|b1|B|b2|C ordering: B's sIJ
// readers drain at b2 before next A writes; C's rs readers drain at next b1
// before next B writes. 13.5 KB LDS, launch_bounds(256,5).

#define NB   2
#define NDIM 160
#define TILE 16
#define RE   24                  // TILE + 8 halo
#define DCHUNK 20
#define NCH  (NDIM / DCHUNK)     // 8 chunks
#define PLANE (NDIM * NDIM)

__global__ __launch_bounds__(256, 5)
void ncc_main(const float* __restrict__ I, const float* __restrict__ J,
              double* __restrict__ out_acc) {
    const int t  = threadIdx.x;
    const int tx = t & 15;
    const int ty = t >> 4;
    const int w0 = blockIdx.x * TILE;
    const int h0 = blockIdx.y * TILE;
    const int b  = blockIdx.z / NCH;
    const int d0 = (blockIdx.z % NCH) * DCHUNK;

    const float* gI = I + (size_t)b * NDIM * PLANE;
    const float* gJ = J + (size_t)b * NDIM * PLANE;

    // Single-buffered LDS (see header comment for the race-freedom argument).
    __shared__ float4 sI4[RE][7];       // halo, 6 chunks + 1 pad
    __shared__ float4 sJ4[RE][7];
    __shared__ float4 rsv[RE][17];      // row sums {I, J, I2, J2}, stride 17
    __shared__ float  rss[RE][17];      // row sums IJ
    __shared__ double wsum[4];

    // D-window ring in registers; slot j is always a compile-time constant.
    float ring[9][5];
#pragma unroll
    for (int k = 0; k < 9; ++k)
#pragma unroll
        for (int c = 0; c < 5; ++c) ring[k][c] = 0.0f;

    float acc[5] = {0.f, 0.f, 0.f, 0.f, 0.f};
    double csum = 0.0;
    const float inv_win = 1.0f / 729.0f;

    // 36 steps: 28 real slices (dz = d0-4+step, clipped), 8 dummy.
    // Output d = d0 + step - 8 emitted for step in [8, 28).
    for (int o = 0; o < 4; ++o) {
#pragma unroll
        for (int j = 0; j < 9; ++j) {
            const int step = o * 9 + j;
            const int dz = d0 - 4 + step;
            float s0 = 0.f, s1 = 0.f, s2 = 0.f, s3 = 0.f, s4 = 0.f;
            if (step < DCHUNK + 8 && dz >= 0 && dz < NDIM) {  // block-uniform
                const float* pI = gI + (size_t)dz * PLANE;
                const float* pJ = gJ + (size_t)dz * PLANE;
                // ---- Phase A: stage 24x24 halo as aligned float4 chunks.
                for (int e = t; e < 288; e += 256) {
                    int f   = e / 144;
                    int rem = e - f * 144;
                    int r   = rem / 6;
                    int c   = rem - r * 6;
                    int h = h0 - 4 + r;
                    int w = w0 - 4 + (c << 2);   // 16B aligned; chunk all-in/all-out
                    float4 v = make_float4(0.f, 0.f, 0.f, 0.f);
                    if ((unsigned)h < NDIM && (unsigned)w < NDIM)
                        v = *(const float4*)((f ? pJ : pI) + h * NDIM + w);
                    if (f) sJ4[r][c] = v; else sI4[r][c] = v;
                }
                __syncthreads();
                // ---- Phase B: sliding 9-tap row sums along W.
                // 96 threads; thread (row r, quad q) -> outputs 4q..4q+3.
                // Explicit scalars only.
                if (t < 96) {
                    const int r = t >> 2, q = t & 3;
                    const float4 A0 = sI4[r][q], A1 = sI4[r][q + 1], A2 = sI4[r][q + 2];
                    const float4 B0 = sJ4[r][q], B1 = sJ4[r][q + 1], B2 = sJ4[r][q + 2];
                    const float ia = A0.x, ib = A0.y, ic = A0.z, id = A0.w;
                    const float ie = A1.x, if_ = A1.y, ig = A1.z, ih = A1.w;
                    const float ii = A2.x, ij = A2.y, ik = A2.z, il = A2.w;
                    const float ja = B0.x, jb = B0.y, jc = B0.z, jd = B0.w;
                    const float je = B1.x, jf = B1.y, jg = B1.z, jh = B1.w;
                    const float ji = B2.x, jj = B2.y, jk = B2.z, jl = B2.w;
                    const int wo = q << 2;
                    float aI  = ia + ib + ic + id + ie + if_ + ig + ih + ii;
                    float aJ  = ja + jb + jc + jd + je + jf + jg + jh + ji;
                    float aII = ia*ia + ib*ib + ic*ic + id*id + ie*ie
                              + if_*if_ + ig*ig + ih*ih + ii*ii;
                    float aJJ = ja*ja + jb*jb + jc*jc + jd*jd + je*je
                              + jf*jf + jg*jg + jh*jh + ji*ji;
                    float aIJ = ia*ja + ib*jb + ic*jc + id*jd + ie*je
                              + if_*jf + ig*jg + ih*jh + ii*ji;
                    rsv[r][wo] = make_float4(aI, aJ, aII, aJJ);
                    rss[r][wo] = aIJ;
                    // slide +1: add (ij,jj), drop (ia,ja)
                    aI  += ij - ia;            aJ  += jj - ja;
                    aII += ij*ij - ia*ia;      aJJ += jj*jj - ja*ja;
                    aIJ += ij*jj - ia*ja;
                    rsv[r][wo + 1] = make_float4(aI, aJ, aII, aJJ);
                    rss[r][wo + 1] = aIJ;
                    // slide +2: add (ik,jk), drop (ib,jb)
                    aI  += ik - ib;            aJ  += jk - jb;
                    aII += ik*ik - ib*ib;      aJJ += jk*jk - jb*jb;
                    aIJ += ik*jk - ib*jb;
                    rsv[r][wo + 2] = make_float4(aI, aJ, aII, aJJ);
                    rss[r][wo + 2] = aIJ;
                    // slide +3: add (il,jl), drop (ic,jc)
                    aI  += il - ic;            aJ  += jl - jc;
                    aII += il*il - ic*ic;      aJJ += jl*jl - jc*jc;
                    aIJ += il*jl - ic*jc;
                    rsv[r][wo + 3] = make_float4(aI, aJ, aII, aJJ);
                    rss[r][wo + 3] = aIJ;
                }
                __syncthreads();
                // ---- Phase C: 9-tap column sums along H at (ty, tx).
#pragma unroll
                for (int k = 0; k < 9; ++k) {
                    float4 v = rsv[ty + k][tx];
                    s0 += v.x; s1 += v.y; s2 += v.z; s3 += v.w;
                    s4 += rss[ty + k][tx];
                }
            }
            // Slide the D-window (constant slot j -> registers).
            acc[0] += s0 - ring[j][0]; ring[j][0] = s0;
            acc[1] += s1 - ring[j][1]; ring[j][1] = s1;
            acc[2] += s2 - ring[j][2]; ring[j][2] = s2;
            acc[3] += s3 - ring[j][3]; ring[j][3] = s3;
            acc[4] += s4 - ring[j][4]; ring[j][4] = s4;
            if (step >= 8 && step < DCHUNK + 8) {
                float Is = acc[0], Js = acc[1];
                float I2 = acc[2], J2 = acc[3], IJ = acc[4];
                float cross = IJ - Is * Js * inv_win;
                float Ivar  = I2 - Is * Is * inv_win;
                float Jvar  = J2 - Js * Js * inv_win;
                float cc = cross * cross / (Ivar * Jvar + 1e-5f);
                csum += (double)cc;
            }
        }
    }

    // Block reduction: wave shuffle, then cross-wave via LDS.
#pragma unroll
    for (int off = 32; off > 0; off >>= 1)
        csum += __shfl_down(csum, off, 64);
    if ((t & 63) == 0) wsum[t >> 6] = csum;
    __syncthreads();
    if (t == 0) {
        double total = wsum[0] + wsum[1] + wsum[2] + wsum[3];
        atomicAdd(out_acc, total);
    }
}

__global__ void ncc_finalize(const double* __restrict__ acc,
                             float* __restrict__ out) {
    out[0] = (float)(-acc[0] / 8192000.0);
}

extern "C" void kernel_launch(void* const* d_in, const int* in_sizes, int n_in,
                              void* d_out, int out_size, void* d_ws, size_t ws_size,
                              hipStream_t stream) {
    const float* I = (const float*)d_in[0];   // y_true
    const float* J = (const float*)d_in[1];   // y_pred
    double* acc = (double*)d_ws;

    hipMemsetAsync(acc, 0, sizeof(double), stream);

    dim3 grid(NDIM / TILE, NDIM / TILE, NB * NCH);  // 10 x 10 x 16
    ncc_main<<<grid, 256, 0, stream>>>(I, J, acc);
    ncc_finalize<<<1, 1, 0, stream>>>(acc, (float*)d_out);
}

// Round 5
// 180.748 us; speedup vs baseline: 1.4843x; 1.4843x over previous
//
#include <hip/hip_runtime.h>
#include <hip/hip_bf16.h>

// NCC loss: five 9x9x9 box sums over (2,1,160,160,160) fp32, fully fused.
// Block owns 16x16 (h,w) tile, streams 20 outputs along D; D-window ring in
// registers (slot index compile-time via outer x unrolled-9 loop).
// Phase A: float4 halo staging (chunk-aligned OOB predication).
// Phase B: sliding 9-tap row sums, 96 threads x 4 outputs, explicit scalars.
// Phase C: 9-tap column sums, 1 output/thread.
// Single-buffered LDS is race-free with A|b1|B|b2|C: B's sIJ readers drain at
// b2 before next A writes; C's rs readers drain at next b1 before next B.
//
// OCCUPANCY NOTE (round 3/4 lesson): waves/EU quantizes at VGPR={64,128,256}.
// __launch_bounds__(256,5) forces the allocator to <=64 VGPRs -> the 45-reg
// D-ring spills to scratch (WRITE_SIZE ballooned 31KB -> 233MB). (256,4)
// gives a 128-VGPR budget: ring stays in registers, zero spill.

#define NB   2
#define NDIM 160
#define TILE 16
#define RE   24                  // TILE + 8 halo
#define DCHUNK 20
#define NCH  (NDIM / DCHUNK)     // 8 chunks
#define PLANE (NDIM * NDIM)

__global__ __launch_bounds__(256, 4)
void ncc_main(const float* __restrict__ I, const float* __restrict__ J,
              double* __restrict__ out_acc) {
    const int t  = threadIdx.x;
    const int tx = t & 15;
    const int ty = t >> 4;
    const int w0 = blockIdx.x * TILE;
    const int h0 = blockIdx.y * TILE;
    const int b  = blockIdx.z / NCH;
    const int d0 = (blockIdx.z % NCH) * DCHUNK;

    const float* gI = I + (size_t)b * NDIM * PLANE;
    const float* gJ = J + (size_t)b * NDIM * PLANE;

    __shared__ float4 sI4[RE][7];       // halo, 6 chunks + 1 pad
    __shared__ float4 sJ4[RE][7];
    __shared__ float4 rsv[RE][17];      // row sums {I, J, I2, J2}, stride 17
    __shared__ float  rss[RE][17];      // row sums IJ
    __shared__ double wsum[4];

    // D-window ring in registers; slot j is always a compile-time constant.
    float ring[9][5];
#pragma unroll
    for (int k = 0; k < 9; ++k)
#pragma unroll
        for (int c = 0; c < 5; ++c) ring[k][c] = 0.0f;

    float acc[5] = {0.f, 0.f, 0.f, 0.f, 0.f};
    double csum = 0.0;
    const float inv_win = 1.0f / 729.0f;

    // 36 steps: 28 real slices (dz = d0-4+step, clipped), 8 dummy.
    // Output d = d0 + step - 8 emitted for step in [8, 28).
    for (int o = 0; o < 4; ++o) {
#pragma unroll
        for (int j = 0; j < 9; ++j) {
            const int step = o * 9 + j;
            const int dz = d0 - 4 + step;
            float s0 = 0.f, s1 = 0.f, s2 = 0.f, s3 = 0.f, s4 = 0.f;
            if (step < DCHUNK + 8 && dz >= 0 && dz < NDIM) {  // block-uniform
                const float* pI = gI + (size_t)dz * PLANE;
                const float* pJ = gJ + (size_t)dz * PLANE;
                // ---- Phase A: stage 24x24 halo as aligned float4 chunks.
                for (int e = t; e < 288; e += 256) {
                    int f   = e / 144;
                    int rem = e - f * 144;
                    int r   = rem / 6;
                    int c   = rem - r * 6;
                    int h = h0 - 4 + r;
                    int w = w0 - 4 + (c << 2);   // 16B aligned; chunk all-in/all-out
                    float4 v = make_float4(0.f, 0.f, 0.f, 0.f);
                    if ((unsigned)h < NDIM && (unsigned)w < NDIM)
                        v = *(const float4*)((f ? pJ : pI) + h * NDIM + w);
                    if (f) sJ4[r][c] = v; else sI4[r][c] = v;
                }
                __syncthreads();
                // ---- Phase B: sliding 9-tap row sums along W.
                // 96 threads; thread (row r, quad q) -> outputs 4q..4q+3.
                if (t < 96) {
                    const int r = t >> 2, q = t & 3;
                    const float4 A0 = sI4[r][q], A1 = sI4[r][q + 1], A2 = sI4[r][q + 2];
                    const float4 B0 = sJ4[r][q], B1 = sJ4[r][q + 1], B2 = sJ4[r][q + 2];
                    const float ia = A0.x, ib = A0.y, ic = A0.z, id = A0.w;
                    const float ie = A1.x, if_ = A1.y, ig = A1.z, ih = A1.w;
                    const float ii = A2.x, ij = A2.y, ik = A2.z, il = A2.w;
                    const float ja = B0.x, jb = B0.y, jc = B0.z, jd = B0.w;
                    const float je = B1.x, jf = B1.y, jg = B1.z, jh = B1.w;
                    const float ji = B2.x, jj = B2.y, jk = B2.z, jl = B2.w;
                    const int wo = q << 2;
                    float aI  = ia + ib + ic + id + ie + if_ + ig + ih + ii;
                    float aJ  = ja + jb + jc + jd + je + jf + jg + jh + ji;
                    float aII = ia*ia + ib*ib + ic*ic + id*id + ie*ie
                              + if_*if_ + ig*ig + ih*ih + ii*ii;
                    float aJJ = ja*ja + jb*jb + jc*jc + jd*jd + je*je
                              + jf*jf + jg*jg + jh*jh + ji*ji;
                    float aIJ = ia*ja + ib*jb + ic*jc + id*jd + ie*je
                              + if_*jf + ig*jg + ih*jh + ii*ji;
                    rsv[r][wo] = make_float4(aI, aJ, aII, aJJ);
                    rss[r][wo] = aIJ;
                    aI  += ij - ia;            aJ  += jj - ja;
                    aII += ij*ij - ia*ia;      aJJ += jj*jj - ja*ja;
                    aIJ += ij*jj - ia*ja;
                    rsv[r][wo + 1] = make_float4(aI, aJ, aII, aJJ);
                    rss[r][wo + 1] = aIJ;
                    aI  += ik - ib;            aJ  += jk - jb;
                    aII += ik*ik - ib*ib;      aJJ += jk*jk - jb*jb;
                    aIJ += ik*jk - ib*jb;
                    rsv[r][wo + 2] = make_float4(aI, aJ, aII, aJJ);
                    rss[r][wo + 2] = aIJ;
                    aI  += il - ic;            aJ  += jl - jc;
                    aII += il*il - ic*ic;      aJJ += jl*jl - jc*jc;
                    aIJ += il*jl - ic*jc;
                    rsv[r][wo + 3] = make_float4(aI, aJ, aII, aJJ);
                    rss[r][wo + 3] = aIJ;
                }
                __syncthreads();
                // ---- Phase C: 9-tap column sums along H at (ty, tx).
#pragma unroll
                for (int k = 0; k < 9; ++k) {
                    float4 v = rsv[ty + k][tx];
                    s0 += v.x; s1 += v.y; s2 += v.z; s3 += v.w;
                    s4 += rss[ty + k][tx];
                }
            }
            // Slide the D-window (constant slot j -> registers).
            acc[0] += s0 - ring[j][0]; ring[j][0] = s0;
            acc[1] += s1 - ring[j][1]; ring[j][1] = s1;
            acc[2] += s2 - ring[j][2]; ring[j][2] = s2;
            acc[3] += s3 - ring[j][3]; ring[j][3] = s3;
            acc[4] += s4 - ring[j][4]; ring[j][4] = s4;
            if (step >= 8 && step < DCHUNK + 8) {
                float Is = acc[0], Js = acc[1];
                float I2 = acc[2], J2 = acc[3], IJ = acc[4];
                float cross = IJ - Is * Js * inv_win;
                float Ivar  = I2 - Is * Is * inv_win;
                float Jvar  = J2 - Js * Js * inv_win;
                float cc = cross * cross / (Ivar * Jvar + 1e-5f);
                csum += (double)cc;
            }
        }
    }

    // Block reduction: wave shuffle, then cross-wave via LDS.
#pragma unroll
    for (int off = 32; off > 0; off >>= 1)
        csum += __shfl_down(csum, off, 64);
    if ((t & 63) == 0) wsum[t >> 6] = csum;
    __syncthreads();
    if (t == 0) {
        double total = wsum[0] + wsum[1] + wsum[2] + wsum[3];
        atomicAdd(out_acc, total);
    }
}

__global__ void ncc_finalize(const double* __restrict__ acc,
                             float* __restrict__ out) {
    out[0] = (float)(-acc[0] / 8192000.0);
}

extern "C" void kernel_launch(void* const* d_in, const int* in_sizes, int n_in,
                              void* d_out, int out_size, void* d_ws, size_t ws_size,
                              hipStream_t stream) {
    const float* I = (const float*)d_in[0];   // y_true
    const float* J = (const float*)d_in[1];   // y_pred
    double* acc = (double*)d_ws;

    hipMemsetAsync(acc, 0, sizeof(double), stream);

    dim3 grid(NDIM / TILE, NDIM / TILE, NB * NCH);  // 10 x 10 x 16
    ncc_main<<<grid, 256, 0, stream>>>(I, J, acc);
    ncc_finalize<<<1, 1, 0, stream>>>(acc, (float*)d_out);
}